// Round 9
// baseline (129.323 us; speedup 1.0000x reference)
//
#include <hip/hip_runtime.h>

#define B_   8
#define C_   512
#define HW_  1024
#define NCOL (B_*HW_)   /* 8192 */
#define NROWS 192
#define EPS  1e-5f

/* ws layout (float offsets) */
#define YOFF   0
#define YSZ    (NROWS*NCOL)            /* 1,572,864 */
#define SPOFF  (YOFF+YSZ)              /* published scF[64] sfF[64] scG[64] sfG[64] */
#define SPSZ   256
#define SP2OFF (SPOFF+SPSZ)            /* per-block stat partials [256][128][2] */
#define SP2SZ  (256*256)
#define CMOFF  (SP2OFF+SP2SZ)          /* [24][4096] : Cf,Cg,T per batch */
#define CMSZ   (24*4096)
#define ISOFF  (CMOFF+CMSZ)            /* inv sigma [8] pad 16 */
#define UOFF   (ISOFF+16)              /* U_raw [8][512][64] */

typedef unsigned short u16;
typedef __attribute__((ext_vector_type(8))) short short8;
typedef __attribute__((ext_vector_type(4))) float f32x4;

__device__ __forceinline__ u16 f2bf(float f) {          /* rounded */
  unsigned u = __float_as_uint(f);
  unsigned r = u + 0x7fffu + ((u >> 16) & 1u);
  return (u16)(r >> 16);
}
__device__ __forceinline__ float bf2f(u16 h) {
  return __uint_as_float(((unsigned)h) << 16);
}
/* truncation split of 8 consecutive f32 -> bf16 hi/lo (cheap, used for W) */
__device__ __forceinline__ void wsplit8(const float* p, short8& hi, short8& lo) {
  #pragma unroll
  for (int i = 0; i < 8; ++i) {
    const float v = p[i];
    const unsigned u = __float_as_uint(v);
    const u16 h = (u16)(u >> 16);
    const float r = v - __uint_as_float(((unsigned)h) << 16);
    const u16 l = (u16)(__float_as_uint(r) >> 16);
    hi[i] = (short)h; lo[i] = (short)l;
  }
}
#define MFMA_B16(a,b,c) __builtin_amdgcn_mfma_f32_16x16x32_bf16(a,b,c,0,0,0)

#define FMA16(a, bb) \
  acc[0][0]+=a.x*bb.x; acc[0][1]+=a.x*bb.y; acc[0][2]+=a.x*bb.z; acc[0][3]+=a.x*bb.w; \
  acc[1][0]+=a.y*bb.x; acc[1][1]+=a.y*bb.y; acc[1][2]+=a.y*bb.z; acc[1][3]+=a.y*bb.w; \
  acc[2][0]+=a.z*bb.x; acc[2][1]+=a.z*bb.y; acc[2][2]+=a.z*bb.z; acc[2][3]+=a.z*bb.w; \
  acc[3][0]+=a.w*bb.x; acc[3][1]+=a.w*bb.y; acc[3][2]+=a.w*bb.z; acc[3][3]+=a.w*bb.w;

/* ---- Stage 1: Y = [Wf;Wg;Wh] @ X + bias; W split on the fly; per-block BN stat partials ---- */
__global__ __launch_bounds__(256) void k_conv(
    const float* __restrict__ x,
    const float* __restrict__ Wf, const float* __restrict__ Wg, const float* __restrict__ Wh,
    const float* __restrict__ bf, const float* __restrict__ bg, const float* __restrict__ bh,
    float* __restrict__ ws)
{
  __shared__ u16 Xh[8*32*8];
  __shared__ u16 Xl[8*32*8];
  const int bid = blockIdx.x;
  const int n0  = bid * 32;
  const int b   = n0 >> 10;
  const int hw0 = n0 & 1023;
  const int t   = threadIdx.x;
  const int lane = t & 63;
  const int wid  = t >> 6;
  const int wrow0 = wid * 48;
  const int cst = t & 31, kg2 = t >> 5;
  const int lm = lane & 15, lk = lane >> 4;

  /* per-(mt) W row pointer (row range verified within a single 64-row block) */
  const float* Wrow[3];
  #pragma unroll
  for (int mt = 0; mt < 3; ++mt) {
    const int row = wrow0 + mt*16 + lm;
    Wrow[mt] = (row < 64)  ? Wf + (size_t)row*C_
             : (row < 128) ? Wg + (size_t)(row-64)*C_
             :               Wh + (size_t)(row-128)*C_;
  }

  f32x4 acc[3][2];
  #pragma unroll
  for (int i=0;i<3;++i) { acc[i][0]=(f32x4)0.f; acc[i][1]=(f32x4)0.f; }

  for (int j = 0; j < 8; ++j) {
    const int kk = j*64;
    __syncthreads();
    {
      const float* xp = x + ((size_t)(b*C_ + kk + kg2*8))*HW_ + hw0 + cst;
      u16 hb[8], lb[8];
      #pragma unroll
      for (int i=0;i<8;++i) {
        const float v = xp[(size_t)i*HW_];
        hb[i] = f2bf(v); lb[i] = f2bf(v - bf2f(hb[i]));
      }
      uint4 ph, pl;
      ph.x=(unsigned)hb[0]|((unsigned)hb[1]<<16); ph.y=(unsigned)hb[2]|((unsigned)hb[3]<<16);
      ph.z=(unsigned)hb[4]|((unsigned)hb[5]<<16); ph.w=(unsigned)hb[6]|((unsigned)hb[7]<<16);
      pl.x=(unsigned)lb[0]|((unsigned)lb[1]<<16); pl.y=(unsigned)lb[2]|((unsigned)lb[3]<<16);
      pl.z=(unsigned)lb[4]|((unsigned)lb[5]<<16); pl.w=(unsigned)lb[6]|((unsigned)lb[7]<<16);
      *reinterpret_cast<uint4*>(&Xh[(kg2*32+cst)*8]) = ph;
      *reinterpret_cast<uint4*>(&Xl[(kg2*32+cst)*8]) = pl;
    }
    __syncthreads();
    #pragma unroll
    for (int kb = 0; kb < 2; ++kb) {
      short8 bhf[2], blf[2];
      #pragma unroll
      for (int nt = 0; nt < 2; ++nt) {
        const int col = nt*16 + lm;
        const int idx = ((kb*4 + lk)*32 + col)*8;
        bhf[nt] = *reinterpret_cast<const short8*>(&Xh[idx]);
        blf[nt] = *reinterpret_cast<const short8*>(&Xl[idx]);
      }
      #pragma unroll
      for (int mt = 0; mt < 3; ++mt) {
        float wv[8];
        *reinterpret_cast<float4*>(&wv[0]) = *reinterpret_cast<const float4*>(&Wrow[mt][kk + kb*32 + lk*8]);
        *reinterpret_cast<float4*>(&wv[4]) = *reinterpret_cast<const float4*>(&Wrow[mt][kk + kb*32 + lk*8 + 4]);
        short8 ah, al;
        wsplit8(wv, ah, al);
        #pragma unroll
        for (int nt = 0; nt < 2; ++nt) {
          acc[mt][nt] = MFMA_B16(ah, bhf[nt], acc[mt][nt]);
          acc[mt][nt] = MFMA_B16(al, bhf[nt], acc[mt][nt]);
          acc[mt][nt] = MFMA_B16(ah, blf[nt], acc[mt][nt]);
        }
      }
    }
  }
  /* epilogue: bias + Y store + per-block stat partials (rows<128, no atomics) */
  #pragma unroll
  for (int mt = 0; mt < 3; ++mt) {
    const int rbase = wrow0 + mt*16;
    const float* bp = (rbase < 64) ? bf : (rbase < 128) ? bg : bh;
    const int rloc0 = (rbase & 63) + lk*4;
    #pragma unroll
    for (int r = 0; r < 4; ++r) {
      const int row = rbase + lk*4 + r;
      const float bi = bp[rloc0 + r];
      const float y0 = acc[mt][0][r] + bi;
      const float y1 = acc[mt][1][r] + bi;
      ws[YOFF + (size_t)row*NCOL + n0 + lm]      = y0;
      ws[YOFF + (size_t)row*NCOL + n0 + 16 + lm] = y1;
      if (rbase < 128) {           /* wave-uniform branch */
        float s  = y0 + y1;
        float s2 = y0*y0 + y1*y1;
        #pragma unroll
        for (int off = 1; off < 16; off <<= 1) {
          s  += __shfl_xor(s,  off);
          s2 += __shfl_xor(s2, off);
        }
        if (lm == 0) {
          ws[SP2OFF + bid*256 + row*2 + 0] = s;
          ws[SP2OFF + bid*256 + row*2 + 1] = s2;
        }
      }
    }
  }
}

/* ---- Stage 2: full-K Gram trio.  grid (3 which, 8 b).
   which 0: Cf = F F^T, 1: Cg = G G^T, 2: T = H G^T.  Writes CM directly. ---- */
__global__ __launch_bounds__(256) void k_gram(
    const float* __restrict__ gamma_f, const float* __restrict__ beta_f,
    const float* __restrict__ gamma_g, const float* __restrict__ beta_g,
    float* __restrict__ ws)
{
  __shared__ u16 Ah[64][72], Al[64][72];
  __shared__ u16 Bh[64][72], Bl[64][72];
  __shared__ float tot[256];
  __shared__ float scs[128], sfs[128];
  const int which = blockIdx.x, b = blockIdx.y;
  const int t = threadIdx.x;

  /* inline stats reduction over 256 block-partials (coalesced, L2-resident) */
  {
    float s = 0.f;
    const float* sp = ws + SP2OFF + t;
    #pragma unroll 8
    for (int blk = 0; blk < 256; ++blk) s += sp[blk*256];
    tot[t] = s;
  }
  __syncthreads();
  if (t < 128) {
    const float s = tot[t*2], s2 = tot[t*2+1];
    const float mean = s*(1.0f/NCOL);
    const float var  = s2*(1.0f/NCOL) - mean*mean;
    const float g  = (t < 64) ? gamma_f[t] : gamma_g[t-64];
    const float be = (t < 64) ? beta_f[t]  : beta_g[t-64];
    const float sc = g * rsqrtf(var + EPS);
    const float sf = be - mean*sc;
    scs[t] = sc; sfs[t] = sf;
    if (which == 0 && b == 0) {      /* publish for k_final */
      const int jj = (t < 64) ? t : t + 64;
      ws[SPOFF + jj]      = sc;
      ws[SPOFF + jj + 64] = sf;
    }
  }
  __syncthreads();

  const int ybaseA = (which==0) ? 0 : (which==1) ? 64 : 128;
  const bool bnA   = (which != 2);
  const int scoA   = (which==1) ? 64 : 0;
  const int bcol0  = b*1024;
  const int lane = t & 63, wid = t >> 6;
  const int lm = lane & 15, lk = lane >> 4;
  const int mt0 = (wid >> 1)*2, nt0 = (wid & 1)*2;

  f32x4 acc2[2][2];
  #pragma unroll
  for (int i=0;i<2;++i) for (int j=0;j<2;++j) acc2[i][j]=(f32x4)0.f;

  for (int kk = 0; kk < 1024; kk += 64) {
    __syncthreads();
    /* stage A (BN+relu for F/G; raw for H) */
    for (int q = t; q < 1024; q += 256) {
      const int r = q >> 4, c4 = (q & 15)*4;
      const float4 v = *reinterpret_cast<const float4*>(
          &ws[YOFF + (size_t)(ybaseA + r)*NCOL + bcol0 + kk + c4]);
      float v0, v1, v2, v3;
      if (bnA) {
        const float sc = scs[scoA + r], sf = sfs[scoA + r];
        v0 = fmaxf(sc*v.x+sf, 0.f); v1 = fmaxf(sc*v.y+sf, 0.f);
        v2 = fmaxf(sc*v.z+sf, 0.f); v3 = fmaxf(sc*v.w+sf, 0.f);
      } else { v0=v.x; v1=v.y; v2=v.z; v3=v.w; }
      const u16 h0=f2bf(v0), h1=f2bf(v1), h2=f2bf(v2), h3=f2bf(v3);
      uint2 ph; ph.x=(unsigned)h0|((unsigned)h1<<16); ph.y=(unsigned)h2|((unsigned)h3<<16);
      uint2 pl;
      pl.x=(unsigned)f2bf(v0-bf2f(h0)) | ((unsigned)f2bf(v1-bf2f(h1))<<16);
      pl.y=(unsigned)f2bf(v2-bf2f(h2)) | ((unsigned)f2bf(v3-bf2f(h3))<<16);
      *reinterpret_cast<uint2*>(&Ah[r][c4]) = ph;
      *reinterpret_cast<uint2*>(&Al[r][c4]) = pl;
    }
    if (which == 2) {   /* stage B = BN'd G */
      for (int q = t; q < 1024; q += 256) {
        const int r = q >> 4, c4 = (q & 15)*4;
        const float4 v = *reinterpret_cast<const float4*>(
            &ws[YOFF + (size_t)(64 + r)*NCOL + bcol0 + kk + c4]);
        const float sc = scs[64 + r], sf = sfs[64 + r];
        const float v0 = fmaxf(sc*v.x+sf, 0.f), v1 = fmaxf(sc*v.y+sf, 0.f);
        const float v2 = fmaxf(sc*v.z+sf, 0.f), v3 = fmaxf(sc*v.w+sf, 0.f);
        const u16 h0=f2bf(v0), h1=f2bf(v1), h2=f2bf(v2), h3=f2bf(v3);
        uint2 ph; ph.x=(unsigned)h0|((unsigned)h1<<16); ph.y=(unsigned)h2|((unsigned)h3<<16);
        uint2 pl;
        pl.x=(unsigned)f2bf(v0-bf2f(h0)) | ((unsigned)f2bf(v1-bf2f(h1))<<16);
        pl.y=(unsigned)f2bf(v2-bf2f(h2)) | ((unsigned)f2bf(v3-bf2f(h3))<<16);
        *reinterpret_cast<uint2*>(&Bh[r][c4]) = ph;
        *reinterpret_cast<uint2*>(&Bl[r][c4]) = pl;
      }
    }
    __syncthreads();
    #pragma unroll
    for (int kb = 0; kb < 2; ++kb) {
      const int ko = kb*32 + lk*8;
      short8 ah[2], al[2], bh2[2], bl2[2];
      #pragma unroll
      for (int mi = 0; mi < 2; ++mi) {
        const int row = (mt0+mi)*16 + lm;
        ah[mi] = *reinterpret_cast<const short8*>(&Ah[row][ko]);
        al[mi] = *reinterpret_cast<const short8*>(&Al[row][ko]);
      }
      #pragma unroll
      for (int ni = 0; ni < 2; ++ni) {
        const int row = (nt0+ni)*16 + lm;
        if (which == 2) {
          bh2[ni] = *reinterpret_cast<const short8*>(&Bh[row][ko]);
          bl2[ni] = *reinterpret_cast<const short8*>(&Bl[row][ko]);
        } else {
          bh2[ni] = *reinterpret_cast<const short8*>(&Ah[row][ko]);
          bl2[ni] = *reinterpret_cast<const short8*>(&Al[row][ko]);
        }
      }
      #pragma unroll
      for (int mi = 0; mi < 2; ++mi)
        #pragma unroll
        for (int ni = 0; ni < 2; ++ni) {
          acc2[mi][ni] = MFMA_B16(ah[mi], bh2[ni], acc2[mi][ni]);
          acc2[mi][ni] = MFMA_B16(al[mi], bh2[ni], acc2[mi][ni]);
          acc2[mi][ni] = MFMA_B16(ah[mi], bl2[ni], acc2[mi][ni]);
        }
    }
  }
  float* base = ws + CMOFF + (size_t)(b*3+which)*4096;
  #pragma unroll
  for (int mi = 0; mi < 2; ++mi)
    #pragma unroll
    for (int ni = 0; ni < 2; ++ni) {
      const int col = (nt0+ni)*16 + lm;
      #pragma unroll
      for (int r = 0; r < 4; ++r) {
        const int row = (mt0+mi)*16 + lk*4 + r;
        base[(size_t)row*64 + col] = acc2[mi][ni][r];
      }
    }
}

/* ---- Stage 3: bid<64 -> U_raw = Wv @ T ; bid>=64 -> power iteration 1/sigma ---- */
__global__ __launch_bounds__(256) void k_su(const float* __restrict__ Wv, float* __restrict__ ws)
{
  __shared__ float smA[64][64];
  __shared__ float smB[64][64];
  const int bid = blockIdx.x;
  const int t = threadIdx.x;
  if (bid < 64) {
    const int b = bid >> 3, rt = bid & 7;
    const float* T = ws + CMOFF + (size_t)(b*3+2)*4096;
    for (int q = t; q < 1024; q += 256)
      *(reinterpret_cast<float4*>(&smB[0][0]) + q) = *(reinterpret_cast<const float4*>(T) + q);
    for (int q = t; q < 1024; q += 256) {
      const int row = q >> 4;
      const int c4  = (q & 15) * 4;
      const float4 wv = *reinterpret_cast<const float4*>(&Wv[(size_t)(rt*64+row)*64 + c4]);
      smA[c4+0][row]=wv.x; smA[c4+1][row]=wv.y; smA[c4+2][row]=wv.z; smA[c4+3][row]=wv.w;
    }
    __syncthreads();
    const int ti = t >> 4, tj = t & 15;
    float acc[4][4] = {};
    #pragma unroll
    for (int c = 0; c < 64; ++c) {
      const float4 a  = *reinterpret_cast<const float4*>(&smA[c][ti*4]);
      const float4 bb = *reinterpret_cast<const float4*>(&smB[c][tj*4]);
      FMA16(a, bb)
    }
    #pragma unroll
    for (int i = 0; i < 4; ++i) {
      float4 o; o.x = acc[i][0]; o.y = acc[i][1]; o.z = acc[i][2]; o.w = acc[i][3];
      *reinterpret_cast<float4*>(&ws[UOFF + ((size_t)b*512 + rt*64 + ti*4+i)*64 + tj*4]) = o;
    }
  } else {
    const int b = bid - 64;
    float* vsh = &smA[0][0];
    float* ush = &smA[1][0];
    const float* Cf = ws + CMOFF + (size_t)(b*3+0)*4096;
    const float* Cg = ws + CMOFF + (size_t)(b*3+1)*4096;
    float cfr[64], cgr[64];
    if (t < 64) {
      #pragma unroll
      for (int k4 = 0; k4 < 16; ++k4) {
        const float4 fa = *reinterpret_cast<const float4*>(&Cf[t*64 + k4*4]);
        const float4 fc = *reinterpret_cast<const float4*>(&Cg[t*64 + k4*4]);
        cfr[k4*4+0]=fa.x; cfr[k4*4+1]=fa.y; cfr[k4*4+2]=fa.z; cfr[k4*4+3]=fa.w;
        cgr[k4*4+0]=fc.x; cgr[k4*4+1]=fc.y; cgr[k4*4+2]=fc.z; cgr[k4*4+3]=fc.w;
      }
    }
    float vloc = 0.125f;
    if (t < 64) vsh[t] = vloc;
    __syncthreads();
    const int NIT = 16;
    float lambda = 0.f;
    for (int it = 0; it <= NIT; ++it) {
      if (t < 64) {
        float u0=0.f,u1=0.f,u2=0.f,u3=0.f;
        #pragma unroll
        for (int j4 = 0; j4 < 16; ++j4) {
          const float4 vq = *reinterpret_cast<const float4*>(&vsh[j4*4]);
          u0 += cfr[j4*4+0]*vq.x; u1 += cfr[j4*4+1]*vq.y;
          u2 += cfr[j4*4+2]*vq.z; u3 += cfr[j4*4+3]*vq.w;
        }
        ush[t] = (u0+u1)+(u2+u3);
      }
      __syncthreads();
      float w = 0.f;
      if (t < 64) {
        float w0=0.f,w1=0.f,w2=0.f,w3=0.f;
        #pragma unroll
        for (int j4 = 0; j4 < 16; ++j4) {
          const float4 uq = *reinterpret_cast<const float4*>(&ush[j4*4]);
          w0 += cgr[j4*4+0]*uq.x; w1 += cgr[j4*4+1]*uq.y;
          w2 += cgr[j4*4+2]*uq.z; w3 += cgr[j4*4+3]*uq.w;
        }
        w = (w0+w1)+(w2+w3);
      }
      if (it == NIT) {
        if (t < 64) {
          float num = vloc * w;
          #pragma unroll
          for (int off = 32; off > 0; off >>= 1) num += __shfl_xor(num, off);
          lambda = num;
        }
      } else {
        if (t < 64) {
          float n2 = w*w;
          #pragma unroll
          for (int off = 32; off > 0; off >>= 1) n2 += __shfl_xor(n2, off);
          const float rn = rsqrtf(fmaxf(n2, 1e-30f));
          vloc = w * rn;
        }
        __syncthreads();
        if (t < 64) vsh[t] = vloc;
        __syncthreads();
      }
    }
    if (t == 0) ws[ISOFF + b] = rsqrtf(fmaxf(lambda, 1e-30f));
  }
}

/* ---- Stage 4: out = isig*(U_raw @ F) + bv + x ---- */
__global__ __launch_bounds__(256) void k_final(
    const float* __restrict__ x, const float* __restrict__ bv,
    float* __restrict__ out, const float* __restrict__ ws)
{
  __shared__ float Ut[64][64];
  __shared__ float Fl[64][64];
  __shared__ float scF[64], sfF[64];
  const int nt = blockIdx.x, ot = blockIdx.y, b = blockIdx.z;
  const int t = threadIdx.x;
  if (t < 64) {
    scF[t] = ws[SPOFF + t];
    sfF[t] = ws[SPOFF + 64 + t];
  }
  for (int q = t; q < 1024; q += 256) {
    const int row = q >> 4, k4 = (q & 15)*4;
    const float4 uv = *reinterpret_cast<const float4*>(
        &ws[UOFF + ((size_t)b*512 + ot*64 + row)*64 + k4]);
    Ut[k4+0][row]=uv.x; Ut[k4+1][row]=uv.y; Ut[k4+2][row]=uv.z; Ut[k4+3][row]=uv.w;
  }
  for (int q = t; q < 1024; q += 256) {
    const int k = q >> 4, c4 = (q & 15)*4;
    const float4 yv = *reinterpret_cast<const float4*>(
        &ws[YOFF + (size_t)k*NCOL + b*1024 + nt*64 + c4]);
    Fl[k][c4+0]=yv.x; Fl[k][c4+1]=yv.y; Fl[k][c4+2]=yv.z; Fl[k][c4+3]=yv.w;
  }
  __syncthreads();
  for (int q = t; q < 1024; q += 256) {
    const int k = q >> 4, c4 = (q & 15)*4;
    const float s = scF[k], f = sfF[k];
    Fl[k][c4+0]=fmaxf(s*Fl[k][c4+0]+f,0.f); Fl[k][c4+1]=fmaxf(s*Fl[k][c4+1]+f,0.f);
    Fl[k][c4+2]=fmaxf(s*Fl[k][c4+2]+f,0.f); Fl[k][c4+3]=fmaxf(s*Fl[k][c4+3]+f,0.f);
  }
  __syncthreads();
  const float isig = ws[ISOFF + b];
  const int ti = t >> 4, tj = t & 15;
  float acc[4][4] = {};
  #pragma unroll
  for (int k = 0; k < 64; ++k) {
    const float4 a  = *reinterpret_cast<const float4*>(&Ut[k][ti*4]);
    const float4 bb = *reinterpret_cast<const float4*>(&Fl[k][tj*4]);
    FMA16(a, bb)
  }
  #pragma unroll
  for (int i = 0; i < 4; ++i) {
    const int oc = ot*64 + ti*4 + i;
    const float bvv = bv[oc];
    const size_t base = ((size_t)b*C_ + oc)*HW_ + nt*64 + tj*4;
    const float4 xv = *reinterpret_cast<const float4*>(&x[base]);
    float4 o;
    o.x = acc[i][0]*isig+bvv+xv.x; o.y = acc[i][1]*isig+bvv+xv.y;
    o.z = acc[i][2]*isig+bvv+xv.z; o.w = acc[i][3]*isig+bvv+xv.w;
    *reinterpret_cast<float4*>(&out[base]) = o;
  }
}

extern "C" void kernel_launch(void* const* d_in, const int* in_sizes, int n_in,
                              void* d_out, int out_size, void* d_ws, size_t ws_size,
                              hipStream_t stream) {
  (void)in_sizes; (void)n_in; (void)out_size; (void)ws_size;
  const float* x       = (const float*)d_in[0];
  const float* Wf      = (const float*)d_in[1];
  const float* bf      = (const float*)d_in[2];
  const float* gamma_f = (const float*)d_in[3];
  const float* beta_f  = (const float*)d_in[4];
  const float* Wg      = (const float*)d_in[5];
  const float* bg      = (const float*)d_in[6];
  const float* gamma_g = (const float*)d_in[7];
  const float* beta_g  = (const float*)d_in[8];
  const float* Wh      = (const float*)d_in[9];
  const float* bh      = (const float*)d_in[10];
  const float* Wv      = (const float*)d_in[11];
  const float* bv      = (const float*)d_in[12];
  float* out = (float*)d_out;
  float* ws  = (float*)d_ws;

  k_conv <<<256,          256, 0, stream>>>(x, Wf, Wg, Wh, bf, bg, bh, ws);
  k_gram <<<dim3(3,8),    256, 0, stream>>>(gamma_f, beta_f, gamma_g, beta_g, ws);
  k_su   <<<72,           256, 0, stream>>>(Wv, ws);
  k_final<<<dim3(16,8,8), 256, 0, stream>>>(x, bv, out, ws);
}

// Round 10
// 86.577 us; speedup vs baseline: 1.4937x; 1.4937x over previous
//
#include <hip/hip_runtime.h>

#define B_   8
#define C_   512
#define HW_  1024
#define NCOL (B_*HW_)   /* 8192 */
#define NROWS 192
#define EPS  1e-5f
#define NCHUNK 32

/* ws layout (float offsets) */
#define YOFF   0
#define YSZ    (NROWS*NCOL)            /* 1,572,864 */
#define SPOFF  (YOFF+YSZ)              /* published scF[64] sfF[64] scG[64] sfG[64] */
#define SPSZ   256
#define SP2OFF (SPOFF+SPSZ)            /* per-block stat partials [256][128][2] */
#define SP2SZ  (256*256)
#define CPOFF  (SP2OFF+SP2SZ)          /* partials [8][3][32][4096] */
#define CPSZ   (24*NCHUNK*4096)
#define CMOFF  (CPOFF+CPSZ)            /* reduced [24][4096] */
#define CMSZ   (24*4096)
#define ISOFF  (CMOFF+CMSZ)            /* inv sigma [8] pad 16 */
#define UOFF   (ISOFF+16)              /* U_raw [8][512][64] */

typedef unsigned short u16;
typedef __attribute__((ext_vector_type(8))) short short8;
typedef __attribute__((ext_vector_type(4))) float f32x4;

__device__ __forceinline__ u16 f2bf(float f) {          /* rounded */
  unsigned u = __float_as_uint(f);
  unsigned r = u + 0x7fffu + ((u >> 16) & 1u);
  return (u16)(r >> 16);
}
__device__ __forceinline__ float bf2f(u16 h) {
  return __uint_as_float(((unsigned)h) << 16);
}
/* truncation split of 8 consecutive f32 -> bf16 hi/lo (cheap, used for W) */
__device__ __forceinline__ void wsplit8(const float* p, short8& hi, short8& lo) {
  #pragma unroll
  for (int i = 0; i < 8; ++i) {
    const float v = p[i];
    const unsigned u = __float_as_uint(v);
    const u16 h = (u16)(u >> 16);
    const float r = v - __uint_as_float(((unsigned)h) << 16);
    const u16 l = (u16)(__float_as_uint(r) >> 16);
    hi[i] = (short)h; lo[i] = (short)l;
  }
}
#define MFMA_B16(a,b,c) __builtin_amdgcn_mfma_f32_16x16x32_bf16(a,b,c,0,0,0)

#define FMA16(a, bb) \
  acc[0][0]+=a.x*bb.x; acc[0][1]+=a.x*bb.y; acc[0][2]+=a.x*bb.z; acc[0][3]+=a.x*bb.w; \
  acc[1][0]+=a.y*bb.x; acc[1][1]+=a.y*bb.y; acc[1][2]+=a.y*bb.z; acc[1][3]+=a.y*bb.w; \
  acc[2][0]+=a.z*bb.x; acc[2][1]+=a.z*bb.y; acc[2][2]+=a.z*bb.z; acc[2][3]+=a.z*bb.w; \
  acc[3][0]+=a.w*bb.x; acc[3][1]+=a.w*bb.y; acc[3][2]+=a.w*bb.z; acc[3][3]+=a.w*bb.w;

/* ---- Stage 1: Y = [Wf;Wg;Wh] @ X + bias; W split on the fly; per-block BN stat partials ---- */
__global__ __launch_bounds__(256) void k_conv(
    const float* __restrict__ x,
    const float* __restrict__ Wf, const float* __restrict__ Wg, const float* __restrict__ Wh,
    const float* __restrict__ bf, const float* __restrict__ bg, const float* __restrict__ bh,
    float* __restrict__ ws)
{
  __shared__ u16 Xh[8*32*8];
  __shared__ u16 Xl[8*32*8];
  const int bid = blockIdx.x;
  const int n0  = bid * 32;
  const int b   = n0 >> 10;
  const int hw0 = n0 & 1023;
  const int t   = threadIdx.x;
  const int lane = t & 63;
  const int wid  = t >> 6;
  const int wrow0 = wid * 48;
  const int cst = t & 31, kg2 = t >> 5;
  const int lm = lane & 15, lk = lane >> 4;

  const float* Wrow[3];
  #pragma unroll
  for (int mt = 0; mt < 3; ++mt) {
    const int row = wrow0 + mt*16 + lm;
    Wrow[mt] = (row < 64)  ? Wf + (size_t)row*C_
             : (row < 128) ? Wg + (size_t)(row-64)*C_
             :               Wh + (size_t)(row-128)*C_;
  }

  f32x4 acc[3][2];
  #pragma unroll
  for (int i=0;i<3;++i) { acc[i][0]=(f32x4)0.f; acc[i][1]=(f32x4)0.f; }

  for (int j = 0; j < 8; ++j) {
    const int kk = j*64;
    __syncthreads();
    {
      const float* xp = x + ((size_t)(b*C_ + kk + kg2*8))*HW_ + hw0 + cst;
      u16 hb[8], lb[8];
      #pragma unroll
      for (int i=0;i<8;++i) {
        const float v = xp[(size_t)i*HW_];
        hb[i] = f2bf(v); lb[i] = f2bf(v - bf2f(hb[i]));
      }
      uint4 ph, pl;
      ph.x=(unsigned)hb[0]|((unsigned)hb[1]<<16); ph.y=(unsigned)hb[2]|((unsigned)hb[3]<<16);
      ph.z=(unsigned)hb[4]|((unsigned)hb[5]<<16); ph.w=(unsigned)hb[6]|((unsigned)hb[7]<<16);
      pl.x=(unsigned)lb[0]|((unsigned)lb[1]<<16); pl.y=(unsigned)lb[2]|((unsigned)lb[3]<<16);
      pl.z=(unsigned)lb[4]|((unsigned)lb[5]<<16); pl.w=(unsigned)lb[6]|((unsigned)lb[7]<<16);
      *reinterpret_cast<uint4*>(&Xh[(kg2*32+cst)*8]) = ph;
      *reinterpret_cast<uint4*>(&Xl[(kg2*32+cst)*8]) = pl;
    }
    __syncthreads();
    #pragma unroll
    for (int kb = 0; kb < 2; ++kb) {
      short8 bhf[2], blf[2];
      #pragma unroll
      for (int nt = 0; nt < 2; ++nt) {
        const int col = nt*16 + lm;
        const int idx = ((kb*4 + lk)*32 + col)*8;
        bhf[nt] = *reinterpret_cast<const short8*>(&Xh[idx]);
        blf[nt] = *reinterpret_cast<const short8*>(&Xl[idx]);
      }
      #pragma unroll
      for (int mt = 0; mt < 3; ++mt) {
        float wv[8];
        *reinterpret_cast<float4*>(&wv[0]) = *reinterpret_cast<const float4*>(&Wrow[mt][kk + kb*32 + lk*8]);
        *reinterpret_cast<float4*>(&wv[4]) = *reinterpret_cast<const float4*>(&Wrow[mt][kk + kb*32 + lk*8 + 4]);
        short8 ah, al;
        wsplit8(wv, ah, al);
        #pragma unroll
        for (int nt = 0; nt < 2; ++nt) {
          acc[mt][nt] = MFMA_B16(ah, bhf[nt], acc[mt][nt]);
          acc[mt][nt] = MFMA_B16(al, bhf[nt], acc[mt][nt]);
          acc[mt][nt] = MFMA_B16(ah, blf[nt], acc[mt][nt]);
        }
      }
    }
  }
  /* epilogue: bias + Y store + per-block stat partials (rows<128, no atomics) */
  #pragma unroll
  for (int mt = 0; mt < 3; ++mt) {
    const int rbase = wrow0 + mt*16;
    const float* bp = (rbase < 64) ? bf : (rbase < 128) ? bg : bh;
    const int rloc0 = (rbase & 63) + lk*4;
    #pragma unroll
    for (int r = 0; r < 4; ++r) {
      const int row = rbase + lk*4 + r;
      const float bi = bp[rloc0 + r];
      const float y0 = acc[mt][0][r] + bi;
      const float y1 = acc[mt][1][r] + bi;
      ws[YOFF + (size_t)row*NCOL + n0 + lm]      = y0;
      ws[YOFF + (size_t)row*NCOL + n0 + 16 + lm] = y1;
      if (rbase < 128) {           /* wave-uniform branch */
        float s  = y0 + y1;
        float s2 = y0*y0 + y1*y1;
        #pragma unroll
        for (int off = 1; off < 16; off <<= 1) {
          s  += __shfl_xor(s,  off);
          s2 += __shfl_xor(s2, off);
        }
        if (lm == 0) {
          ws[SP2OFF + bid*256 + row*2 + 0] = s;
          ws[SP2OFF + bid*256 + row*2 + 1] = s2;
        }
      }
    }
  }
}

/* ---- Stage 2: Cf/Cg/T partials, 32-col chunk per block (256 blocks);
       inline coalesced stats reduce; publishes sc/sf once ---- */
__global__ __launch_bounds__(256) void k_cpart(
    const float* __restrict__ gamma_f, const float* __restrict__ beta_f,
    const float* __restrict__ gamma_g, const float* __restrict__ beta_g,
    float* __restrict__ ws)
{
  __shared__ u16 Sh[3][64][40];
  __shared__ u16 Sl[3][64][40];
  __shared__ float tot[256];
  __shared__ float scs[128], sfs[128];
  const int chunk = blockIdx.x, b = blockIdx.y;
  const int t = threadIdx.x;

  /* coalesced reduce of 256 per-block partials (L2-resident) */
  {
    float s = 0.f;
    const float* sp = ws + SP2OFF + t;
    #pragma unroll 8
    for (int blk = 0; blk < 256; ++blk) s += sp[blk*256];
    tot[t] = s;
  }
  __syncthreads();
  if (t < 128) {
    const float s = tot[t*2], s2 = tot[t*2+1];
    const float mean = s*(1.0f/NCOL);
    const float var  = s2*(1.0f/NCOL) - mean*mean;
    const float g  = (t < 64) ? gamma_f[t] : gamma_g[t-64];
    const float be = (t < 64) ? beta_f[t]  : beta_g[t-64];
    const float sc = g * rsqrtf(var + EPS);
    const float sf = be - mean*sc;
    scs[t] = sc; sfs[t] = sf;
    if (chunk == 0 && b == 0) {      /* publish for k_final */
      const int jj = (t < 64) ? t : t + 64;
      ws[SPOFF + jj]      = sc;
      ws[SPOFF + jj + 64] = sf;
    }
  }
  __syncthreads();

  const int bcol0 = b*1024 + chunk*32;
  for (int q = t; q < 1536; q += 256) {
    const int mm = q >> 9, rem = q & 511;
    const int r = rem >> 3, c4 = (rem & 7) * 4;
    const float4 v = *reinterpret_cast<const float4*>(
        &ws[YOFF + (size_t)(mm*64 + r)*NCOL + bcol0 + c4]);
    float v0, v1, v2, v3;
    if (mm < 2) {
      const float sc = scs[mm*64 + r], sf = sfs[mm*64 + r];
      v0 = fmaxf(sc*v.x+sf, 0.f); v1 = fmaxf(sc*v.y+sf, 0.f);
      v2 = fmaxf(sc*v.z+sf, 0.f); v3 = fmaxf(sc*v.w+sf, 0.f);
    } else { v0=v.x; v1=v.y; v2=v.z; v3=v.w; }
    const u16 h0=f2bf(v0), h1=f2bf(v1), h2=f2bf(v2), h3=f2bf(v3);
    uint2 ph; ph.x=(unsigned)h0|((unsigned)h1<<16); ph.y=(unsigned)h2|((unsigned)h3<<16);
    uint2 pl;
    pl.x=(unsigned)f2bf(v0-bf2f(h0)) | ((unsigned)f2bf(v1-bf2f(h1))<<16);
    pl.y=(unsigned)f2bf(v2-bf2f(h2)) | ((unsigned)f2bf(v3-bf2f(h3))<<16);
    *reinterpret_cast<uint2*>(&Sh[mm][r][c4]) = ph;
    *reinterpret_cast<uint2*>(&Sl[mm][r][c4]) = pl;
  }
  __syncthreads();
  {
    const int lane = t & 63, wid = t >> 6;
    const int lm = lane & 15, lk = lane >> 4;
    const int mt0 = (wid >> 1)*2, nt0 = (wid & 1)*2;
    const int ko = lk*8;
    short8 ah[3][2], al[3][2];
    #pragma unroll
    for (int m = 0; m < 3; ++m)
      #pragma unroll
      for (int mi = 0; mi < 2; ++mi) {
        const int row = (mt0+mi)*16 + lm;
        ah[m][mi] = *reinterpret_cast<const short8*>(&Sh[m][row][ko]);
        al[m][mi] = *reinterpret_cast<const short8*>(&Sl[m][row][ko]);
      }
    short8 bhf[2][2], blf[2][2];
    #pragma unroll
    for (int m = 0; m < 2; ++m)
      #pragma unroll
      for (int ni = 0; ni < 2; ++ni) {
        const int row = (nt0+ni)*16 + lm;
        bhf[m][ni] = *reinterpret_cast<const short8*>(&Sh[m][row][ko]);
        blf[m][ni] = *reinterpret_cast<const short8*>(&Sl[m][row][ko]);
      }
    f32x4 acc2[3][2][2];
    #pragma unroll
    for (int p=0;p<3;++p) for (int i=0;i<2;++i) for (int j=0;j<2;++j) acc2[p][i][j]=(f32x4)0.f;
    #pragma unroll
    for (int p = 0; p < 3; ++p) {
      const int am = p;
      const int bm = (p==0) ? 0 : 1;
      #pragma unroll
      for (int mi = 0; mi < 2; ++mi)
        #pragma unroll
        for (int ni = 0; ni < 2; ++ni) {
          acc2[p][mi][ni] = MFMA_B16(ah[am][mi], bhf[bm][ni], acc2[p][mi][ni]);
          acc2[p][mi][ni] = MFMA_B16(al[am][mi], bhf[bm][ni], acc2[p][mi][ni]);
          acc2[p][mi][ni] = MFMA_B16(ah[am][mi], blf[bm][ni], acc2[p][mi][ni]);
        }
    }
    float* cp = ws + CPOFF;
    #pragma unroll
    for (int p = 0; p < 3; ++p) {
      float* base = cp + ((size_t)((b*3+p)*NCHUNK + chunk))*4096;
      #pragma unroll
      for (int mi = 0; mi < 2; ++mi)
        #pragma unroll
        for (int ni = 0; ni < 2; ++ni) {
          const int col = (nt0+ni)*16 + lm;
          #pragma unroll
          for (int r = 0; r < 4; ++r) {
            const int row = (mt0+mi)*16 + lk*4 + r;
            base[(size_t)row*64 + col] = acc2[p][mi][ni][r];
          }
        }
    }
  }
}

/* ---- Stage 3: coalesced chunk reduction: partials -> CM[24][4096] ---- */
__global__ __launch_bounds__(256) void k_creduce(float* __restrict__ ws)
{
  const int m = blockIdx.y;                    /* b*3+p */
  const int q = blockIdx.x*256 + threadIdx.x;  /* 0..1023 float4 index */
  const float4* src = reinterpret_cast<const float4*>(ws + CPOFF) + (size_t)m*NCHUNK*1024;
  float4 s = {0.f,0.f,0.f,0.f};
  #pragma unroll 8
  for (int ch = 0; ch < NCHUNK; ++ch) {
    const float4 p = src[(size_t)ch*1024 + q];
    s.x+=p.x; s.y+=p.y; s.z+=p.z; s.w+=p.w;
  }
  *(reinterpret_cast<float4*>(ws + CMOFF) + (size_t)m*1024 + q) = s;
}

/* ---- Stage 4: bid<64 -> U_raw = Wv @ T ; bid>=64 -> power iteration 1/sigma ---- */
__global__ __launch_bounds__(256) void k_su(const float* __restrict__ Wv, float* __restrict__ ws)
{
  __shared__ float smA[64][64];
  __shared__ float smB[64][64];
  const int bid = blockIdx.x;
  const int t = threadIdx.x;
  if (bid < 64) {
    const int b = bid >> 3, rt = bid & 7;
    const float* T = ws + CMOFF + (size_t)(b*3+2)*4096;
    for (int q = t; q < 1024; q += 256)
      *(reinterpret_cast<float4*>(&smB[0][0]) + q) = *(reinterpret_cast<const float4*>(T) + q);
    for (int q = t; q < 1024; q += 256) {
      const int row = q >> 4;
      const int c4  = (q & 15) * 4;
      const float4 wv = *reinterpret_cast<const float4*>(&Wv[(size_t)(rt*64+row)*64 + c4]);
      smA[c4+0][row]=wv.x; smA[c4+1][row]=wv.y; smA[c4+2][row]=wv.z; smA[c4+3][row]=wv.w;
    }
    __syncthreads();
    const int ti = t >> 4, tj = t & 15;
    float acc[4][4] = {};
    #pragma unroll
    for (int c = 0; c < 64; ++c) {
      const float4 a  = *reinterpret_cast<const float4*>(&smA[c][ti*4]);
      const float4 bb = *reinterpret_cast<const float4*>(&smB[c][tj*4]);
      FMA16(a, bb)
    }
    #pragma unroll
    for (int i = 0; i < 4; ++i) {
      float4 o; o.x = acc[i][0]; o.y = acc[i][1]; o.z = acc[i][2]; o.w = acc[i][3];
      *reinterpret_cast<float4*>(&ws[UOFF + ((size_t)b*512 + rt*64 + ti*4+i)*64 + tj*4]) = o;
    }
  } else {
    const int b = bid - 64;
    float* vsh = &smA[0][0];
    float* ush = &smA[1][0];
    const float* Cf = ws + CMOFF + (size_t)(b*3+0)*4096;
    const float* Cg = ws + CMOFF + (size_t)(b*3+1)*4096;
    float cfr[64], cgr[64];
    if (t < 64) {
      #pragma unroll
      for (int k4 = 0; k4 < 16; ++k4) {
        const float4 fa = *reinterpret_cast<const float4*>(&Cf[t*64 + k4*4]);
        const float4 fc = *reinterpret_cast<const float4*>(&Cg[t*64 + k4*4]);
        cfr[k4*4+0]=fa.x; cfr[k4*4+1]=fa.y; cfr[k4*4+2]=fa.z; cfr[k4*4+3]=fa.w;
        cgr[k4*4+0]=fc.x; cgr[k4*4+1]=fc.y; cgr[k4*4+2]=fc.z; cgr[k4*4+3]=fc.w;
      }
    }
    float vloc = 0.125f;
    if (t < 64) vsh[t] = vloc;
    __syncthreads();
    const int NIT = 16;
    float lambda = 0.f;
    for (int it = 0; it <= NIT; ++it) {
      if (t < 64) {
        float u0=0.f,u1=0.f,u2=0.f,u3=0.f;
        #pragma unroll
        for (int j4 = 0; j4 < 16; ++j4) {
          const float4 vq = *reinterpret_cast<const float4*>(&vsh[j4*4]);
          u0 += cfr[j4*4+0]*vq.x; u1 += cfr[j4*4+1]*vq.y;
          u2 += cfr[j4*4+2]*vq.z; u3 += cfr[j4*4+3]*vq.w;
        }
        ush[t] = (u0+u1)+(u2+u3);
      }
      __syncthreads();
      float w = 0.f;
      if (t < 64) {
        float w0=0.f,w1=0.f,w2=0.f,w3=0.f;
        #pragma unroll
        for (int j4 = 0; j4 < 16; ++j4) {
          const float4 uq = *reinterpret_cast<const float4*>(&ush[j4*4]);
          w0 += cgr[j4*4+0]*uq.x; w1 += cgr[j4*4+1]*uq.y;
          w2 += cgr[j4*4+2]*uq.z; w3 += cgr[j4*4+3]*uq.w;
        }
        w = (w0+w1)+(w2+w3);
      }
      if (it == NIT) {
        if (t < 64) {
          float num = vloc * w;
          #pragma unroll
          for (int off = 32; off > 0; off >>= 1) num += __shfl_xor(num, off);
          lambda = num;
        }
      } else {
        if (t < 64) {
          float n2 = w*w;
          #pragma unroll
          for (int off = 32; off > 0; off >>= 1) n2 += __shfl_xor(n2, off);
          const float rn = rsqrtf(fmaxf(n2, 1e-30f));
          vloc = w * rn;
        }
        __syncthreads();
        if (t < 64) vsh[t] = vloc;
        __syncthreads();
      }
    }
    if (t == 0) ws[ISOFF + b] = rsqrtf(fmaxf(lambda, 1e-30f));
  }
}

/* ---- Stage 5: out = isig*(U_raw @ F) + bv + x ---- */
__global__ __launch_bounds__(256) void k_final(
    const float* __restrict__ x, const float* __restrict__ bv,
    float* __restrict__ out, const float* __restrict__ ws)
{
  __shared__ float Ut[64][64];
  __shared__ float Fl[64][64];
  __shared__ float scF[64], sfF[64];
  const int nt = blockIdx.x, ot = blockIdx.y, b = blockIdx.z;
  const int t = threadIdx.x;
  if (t < 64) {
    scF[t] = ws[SPOFF + t];
    sfF[t] = ws[SPOFF + 64 + t];
  }
  for (int q = t; q < 1024; q += 256) {
    const int row = q >> 4, k4 = (q & 15)*4;
    const float4 uv = *reinterpret_cast<const float4*>(
        &ws[UOFF + ((size_t)b*512 + ot*64 + row)*64 + k4]);
    Ut[k4+0][row]=uv.x; Ut[k4+1][row]=uv.y; Ut[k4+2][row]=uv.z; Ut[k4+3][row]=uv.w;
  }
  for (int q = t; q < 1024; q += 256) {
    const int k = q >> 4, c4 = (q & 15)*4;
    const float4 yv = *reinterpret_cast<const float4*>(
        &ws[YOFF + (size_t)k*NCOL + b*1024 + nt*64 + c4]);
    Fl[k][c4+0]=yv.x; Fl[k][c4+1]=yv.y; Fl[k][c4+2]=yv.z; Fl[k][c4+3]=yv.w;
  }
  __syncthreads();
  for (int q = t; q < 1024; q += 256) {
    const int k = q >> 4, c4 = (q & 15)*4;
    const float s = scF[k], f = sfF[k];
    Fl[k][c4+0]=fmaxf(s*Fl[k][c4+0]+f,0.f); Fl[k][c4+1]=fmaxf(s*Fl[k][c4+1]+f,0.f);
    Fl[k][c4+2]=fmaxf(s*Fl[k][c4+2]+f,0.f); Fl[k][c4+3]=fmaxf(s*Fl[k][c4+3]+f,0.f);
  }
  __syncthreads();
  const float isig = ws[ISOFF + b];
  const int ti = t >> 4, tj = t & 15;
  float acc[4][4] = {};
  #pragma unroll
  for (int k = 0; k < 64; ++k) {
    const float4 a  = *reinterpret_cast<const float4*>(&Ut[k][ti*4]);
    const float4 bb = *reinterpret_cast<const float4*>(&Fl[k][tj*4]);
    FMA16(a, bb)
  }
  #pragma unroll
  for (int i = 0; i < 4; ++i) {
    const int oc = ot*64 + ti*4 + i;
    const float bvv = bv[oc];
    const size_t base = ((size_t)b*C_ + oc)*HW_ + nt*64 + tj*4;
    const float4 xv = *reinterpret_cast<const float4*>(&x[base]);
    float4 o;
    o.x = acc[i][0]*isig+bvv+xv.x; o.y = acc[i][1]*isig+bvv+xv.y;
    o.z = acc[i][2]*isig+bvv+xv.z; o.w = acc[i][3]*isig+bvv+xv.w;
    *reinterpret_cast<float4*>(&out[base]) = o;
  }
}

extern "C" void kernel_launch(void* const* d_in, const int* in_sizes, int n_in,
                              void* d_out, int out_size, void* d_ws, size_t ws_size,
                              hipStream_t stream) {
  (void)in_sizes; (void)n_in; (void)out_size; (void)ws_size;
  const float* x       = (const float*)d_in[0];
  const float* Wf      = (const float*)d_in[1];
  const float* bf      = (const float*)d_in[2];
  const float* gamma_f = (const float*)d_in[3];
  const float* beta_f  = (const float*)d_in[4];
  const float* Wg      = (const float*)d_in[5];
  const float* bg      = (const float*)d_in[6];
  const float* gamma_g = (const float*)d_in[7];
  const float* beta_g  = (const float*)d_in[8];
  const float* Wh      = (const float*)d_in[9];
  const float* bh      = (const float*)d_in[10];
  const float* Wv      = (const float*)d_in[11];
  const float* bv      = (const float*)d_in[12];
  float* out = (float*)d_out;
  float* ws  = (float*)d_ws;

  k_conv   <<<256,             256, 0, stream>>>(x, Wf, Wg, Wh, bf, bg, bh, ws);
  k_cpart  <<<dim3(NCHUNK,8),  256, 0, stream>>>(gamma_f, beta_f, gamma_g, beta_g, ws);
  k_creduce<<<dim3(4,24),      256, 0, stream>>>(ws);
  k_su     <<<72,              256, 0, stream>>>(Wv, ws);
  k_final  <<<dim3(16,8,8),    256, 0, stream>>>(x, bv, out, ws);
}